// Round 6
// baseline (107.684 us; speedup 1.0000x reference)
//
#include <hip/hip_runtime.h>

// OPAM_Small_CatPool: B=256, C=512, CI=128, L=150.
// Round 6: two 2-blocks/CU kernels instead of one 1-block/CU mega-kernel.
//   prep_all: Wqk = Wq^T*Wk -> split bf16 hi/lo; Wv split; cvec = Wk^T*bq
//   k1_v (grid 512 = b x l-half): v = Wv x + bv (MFMA 3-split), writes v packed
//         u32 (hi|lo) to ws + fp32 v-part maxpool/depthwise partials
//   k2_attn (grid 256, 59KB LDS, VGPR<=64): t = Wqk v -> E = v^T t (+svec) ->
//         softmax -> P (LDS, overlays ts) -> att = v_hi P^T -> fused reduce;
//         v operands unpacked from global (L2/L3-resident)
//   tail_pwbn: pw = Wp dw^T + batch-stat BN + relu
// bd/bp dropped (cancel in BN mean subtraction); energy row-constant bias terms
// cancel in softmax; column term kept via svec.

typedef float f32x4  __attribute__((ext_vector_type(4)));
typedef float f32x16 __attribute__((ext_vector_type(16)));
typedef short s16x8  __attribute__((ext_vector_type(8)));
typedef unsigned short BF;

union U8 { s16x8 v; BF u[8]; uint2 d[2]; unsigned w[4]; };

__device__ __forceinline__ BF bfhi(float f) { return (BF)(__float_as_uint(f) >> 16); }
__device__ __forceinline__ float bff(BF h) { return __uint_as_float(((unsigned)h) << 16); }
__device__ __forceinline__ BF bflo(float f, BF hi) { return bfhi(f - bff(hi)); }
__device__ __forceinline__ BF bfrne(float f) {
    unsigned u = __float_as_uint(f);
    u += 0x7fffu + ((u >> 16) & 1u);
    return (BF)(u >> 16);
}
__device__ __forceinline__ s16x8 ld8l(const BF* p) {
    U8 t; t.d[0] = *(const uint2*)p; t.d[1] = *(const uint2*)(p + 4); return t.v;
}
__device__ __forceinline__ void st4(BF* p, BF a, BF b, BF c, BF d) {
    uint2 t; t.x = (unsigned)a | ((unsigned)b << 16);
    t.y = (unsigned)c | ((unsigned)d << 16);
    *(uint2*)p = t;
}
// 8 packed u32 -> hi/lo s16x8 fragments
__device__ __forceinline__ void ldv8(const unsigned* p, s16x8& hi, s16x8& lo) {
    unsigned u[8];
    *(uint4*)&u[0] = *(const uint4*)p;
    *(uint4*)&u[4] = *(const uint4*)(p + 4);
    U8 H, L;
    #pragma unroll
    for (int e = 0; e < 4; ++e) {
        unsigned a = u[2*e], b2 = u[2*e + 1];
        H.w[e] = (a >> 16) | (b2 & 0xffff0000u);
        L.w[e] = (a & 0xffffu) | (b2 << 16);
    }
    hi = H.v; lo = L.v;
}
#define MFMA(a, b, c)   __builtin_amdgcn_mfma_f32_16x16x32_bf16(a, b, c, 0, 0, 0)
#define MFMA32(a, b, c) __builtin_amdgcn_mfma_f32_32x32x16_bf16(a, b, c, 0, 0, 0)

// ------------------------- prep: Wqk + splits + cvec -------------------------
__global__ __launch_bounds__(256)
void prep_all(const float* __restrict__ Wv, const float* __restrict__ Wq,
              const float* __restrict__ Wk, const float* __restrict__ bq,
              BF* __restrict__ wvh, BF* __restrict__ wvl,
              BF* __restrict__ wqh, BF* __restrict__ wql,
              float* __restrict__ cvec)
{
    __shared__ float qs[128][33], ks_[128][33];
    const int blk = blockIdx.x, tid = threadIdx.x;
    if (blk < 64) {
        int i = blk * 1024 + tid * 4;
        float4 v = *(const float4*)(Wv + i);
        BF h0 = bfhi(v.x), h1 = bfhi(v.y), h2 = bfhi(v.z), h3 = bfhi(v.w);
        st4(&wvh[i], h0, h1, h2, h3);
        st4(&wvl[i], bflo(v.x,h0), bflo(v.y,h1), bflo(v.z,h2), bflo(v.w,h3));
    } else if (blk < 80) {
        int bi = blk - 64;
        int d1_0 = (bi >> 2) * 32, d2_0 = (bi & 3) * 32;
        for (int i = tid; i < 4096; i += 256) {
            int o = i >> 5, c = i & 31;
            qs[o][c]  = Wq[o * 128 + d1_0 + c];
            ks_[o][c] = Wk[o * 128 + d2_0 + c];
        }
        __syncthreads();
        #pragma unroll
        for (int j = 0; j < 4; ++j) {
            int idx = j * 256 + tid;
            int d1 = idx >> 5, d2 = idx & 31;
            float s = 0.f;
            #pragma unroll 8
            for (int o = 0; o < 128; ++o) s = fmaf(qs[o][d1], ks_[o][d2], s);
            BF h = bfhi(s);
            wqh[(d1_0 + d1) * 128 + d2_0 + d2] = h;
            wql[(d1_0 + d1) * 128 + d2_0 + d2] = bflo(s, h);
        }
    } else {
        if (tid < 128) {
            float s = 0.f;
            for (int o = 0; o < 128; ++o) s += bq[o] * Wk[o * 128 + tid];
            cvec[tid] = s;
        }
    }
}

// ------------------------- k1: v = Wv x + bv, packed u32 + v-part partials ----
// grid 512 (b x l-half), 512 thr: 4 compute waves + 4 stager waves
__global__ __launch_bounds__(512, 4)
void k1_v(const float* __restrict__ x, const BF* __restrict__ wvh,
          const BF* __restrict__ wvl, const float* __restrict__ bv,
          const float* __restrict__ Wd,
          unsigned* __restrict__ vp, float* __restrict__ vpm,
          float* __restrict__ vpd)
{
    __shared__ BF xt[2][2][80][36];   // [buf][hilo][l-local][c32+pad]
    const int bx = blockIdx.x;
    const int b = bx & 255, lh = bx >> 8;
    const int l0 = lh * 80;
    const float* xb = x + (long)b * 76800 + l0;
    const int tid = threadIdx.x, lane = tid & 63, w = tid >> 6;
    const int li = lane & 15, gq = lane >> 4;

    if (w < 4) {
        // compute wave: c-tiles {w*32 + nf*16}
        f32x4 acc[5][2];
        #pragma unroll
        for (int mf = 0; mf < 5; ++mf)
            #pragma unroll
            for (int nf = 0; nf < 2; ++nf) acc[mf][nf] = f32x4{0.f,0.f,0.f,0.f};
        s16x8 bh[2], bl[2];
        #pragma unroll
        for (int nf = 0; nf < 2; ++nf) {
            long g = (long)(w*32 + nf*16 + li)*512 + gq*8;
            bh[nf] = *(const s16x8*)(wvh + g);
            bl[nf] = *(const s16x8*)(wvl + g);
        }
        __syncthreads();
        for (int p = 0; p < 16; ++p) {
            s16x8 nbh[2], nbl[2];
            if (p < 15) {
                #pragma unroll
                for (int nf = 0; nf < 2; ++nf) {
                    long g = (long)(w*32 + nf*16 + li)*512 + (p+1)*32 + gq*8;
                    nbh[nf] = *(const s16x8*)(wvh + g);
                    nbl[nf] = *(const s16x8*)(wvl + g);
                }
            }
            const BF (*xh)[36] = xt[p & 1][0];
            const BF (*xl)[36] = xt[p & 1][1];
            #pragma unroll
            for (int mf = 0; mf < 5; ++mf) {
                int row = mf*16 + li;
                s16x8 ah = ld8l(&xh[row][gq*8]);
                s16x8 al = ld8l(&xl[row][gq*8]);
                #pragma unroll
                for (int nf = 0; nf < 2; ++nf) {
                    acc[mf][nf] = MFMA(al, bh[nf], acc[mf][nf]);
                    acc[mf][nf] = MFMA(ah, bl[nf], acc[mf][nf]);
                    acc[mf][nf] = MFMA(ah, bh[nf], acc[mf][nf]);
                }
            }
            if (p < 15) {
                #pragma unroll
                for (int nf = 0; nf < 2; ++nf) { bh[nf] = nbh[nf]; bl[nf] = nbl[nf]; }
            }
            __syncthreads();
        }
        // epilogue: +bv, pack u32 store, fp32 v-part max/dot partials
        #pragma unroll
        for (int nf = 0; nf < 2; ++nf) {
            int c = w*32 + nf*16 + li;
            float bvv = bv[c];
            float mx = -3.4e38f, dt = 0.f;
            #pragma unroll
            for (int mf = 0; mf < 5; ++mf)
                #pragma unroll
                for (int r = 0; r < 4; ++r) {
                    int ll = mf*16 + gq*4 + r;
                    float f = acc[mf][nf][r] + bvv;
                    BF h = bfhi(f);
                    BF lo2 = bflo(f, h);
                    vp[((long)b*160 + l0 + ll)*128 + c] = ((unsigned)h << 16) | lo2;
                    if (l0 + ll < 150) {
                        mx = fmaxf(mx, f);
                        dt = fmaf(f, Wd[(128 + c)*150 + l0 + ll], dt);
                    }
                }
            mx = fmaxf(mx, __shfl_xor(mx, 16)); dt += __shfl_xor(dt, 16);
            mx = fmaxf(mx, __shfl_xor(mx, 32)); dt += __shfl_xor(dt, 32);
            if (gq == 0) {
                vpm[((long)lh*256 + b)*128 + c] = mx;
                vpd[((long)lh*256 + b)*128 + c] = dt;
            }
        }
    } else {
        // stager wave: 8 channels per chunk
        const int sw = w - 4;
        const int bound = (lh == 0) ? 16 : 6;   // validity of rows 64+lane
        float cur[2][8];
        auto ldchunk = [&](int p) {
            #pragma unroll
            for (int cc = 0; cc < 8; ++cc) {
                int ch = p*32 + sw*8 + cc;
                cur[0][cc] = xb[ch*150 + lane];
                cur[1][cc] = (lane < bound) ? xb[ch*150 + 64 + lane] : 0.f;
            }
        };
        auto wrchunk = [&](int buf) {
            #pragma unroll
            for (int g2 = 0; g2 < 2; ++g2) {
                BF h0 = bfhi(cur[0][g2*4+0]), h1 = bfhi(cur[0][g2*4+1]);
                BF h2 = bfhi(cur[0][g2*4+2]), h3 = bfhi(cur[0][g2*4+3]);
                st4(&xt[buf][0][lane][sw*8 + g2*4], h0, h1, h2, h3);
                st4(&xt[buf][1][lane][sw*8 + g2*4],
                    bflo(cur[0][g2*4+0],h0), bflo(cur[0][g2*4+1],h1),
                    bflo(cur[0][g2*4+2],h2), bflo(cur[0][g2*4+3],h3));
                if (lane < 16) {
                    BF k0 = bfhi(cur[1][g2*4+0]), k1 = bfhi(cur[1][g2*4+1]);
                    BF k2 = bfhi(cur[1][g2*4+2]), k3 = bfhi(cur[1][g2*4+3]);
                    st4(&xt[buf][0][64 + lane][sw*8 + g2*4], k0, k1, k2, k3);
                    st4(&xt[buf][1][64 + lane][sw*8 + g2*4],
                        bflo(cur[1][g2*4+0],k0), bflo(cur[1][g2*4+1],k1),
                        bflo(cur[1][g2*4+2],k2), bflo(cur[1][g2*4+3],k3));
                }
            }
        };
        ldchunk(0); wrchunk(0); ldchunk(1);
        __syncthreads();
        for (int p = 0; p < 16; ++p) {
            if (p < 15) {
                wrchunk((p + 1) & 1);
                if (p < 14) ldchunk(p + 2);
            }
            __syncthreads();
        }
    }
}

// ------------------------- k2: attention from packed v -------------------------
// grid 256 (1/batch), 1024 thr, LDS 60.7KB -> 2 blocks/CU (needs VGPR<=64)
__global__ __launch_bounds__(1024, 8)
void k2_attn(const unsigned* __restrict__ vp,
             const BF* __restrict__ wqh, const BF* __restrict__ wql,
             const float* __restrict__ cvec, const float* __restrict__ gammap,
             const float* __restrict__ Wd,
             const float* __restrict__ vpm, const float* __restrict__ vpd,
             float* __restrict__ dw, float* __restrict__ out)
{
    __shared__ char smem[60672];
    BF (*ts)[2][192][36] = (BF(*)[2][192][36])smem;   // [s2][hilo][j][c32+pad]
    BF (*P)[172] = (BF(*)[172])smem;                   // overlays ts (by lifetime)
    float* smax = (float*)(smem + 55296);              // [3][160]; later pmax[2][128]
    float* ssum = smax + 480;                          // [3][160]; later pdot[2][128]
    float* svp  = ssum + 480;                          // [2][192]

    const int b = blockIdx.x;
    const unsigned* vb = vp + (long)b * 20480;
    const int tid = threadIdx.x;
    const int lane = tid & 63, w = tid >> 6;
    const int li = lane & 15, gq = lane >> 4;
    const int l31 = lane & 31, hi5 = lane >> 5;
    const float gamma = gammap[0];

    // ================= phase E: t = Wqk v (32x32) ; E = v^T t =================
    f32x4 eacc[2][4];
    #pragma unroll
    for (int a = 0; a < 2; ++a)
        #pragma unroll
        for (int b2 = 0; b2 < 4; ++b2) eacc[a][b2] = f32x4{0.f,0.f,0.f,0.f};
    const int iw = w / 3, jw = w % 3;

    for (int pr = 0; pr < 2; ++pr) {
        if (w < 10) {   // tgemm32: strips 2pr+s2, tiles (s2 2)x(jt 5)
            const int s2 = w / 5, jt = w % 5;
            const int ss = pr*2 + s2;
            f32x16 tacc;
            #pragma unroll
            for (int r = 0; r < 16; ++r) tacc[r] = 0.f;
            const unsigned* arow = vb + (jt*32 + l31)*128;
            const long brow = (long)(ss*32 + l31)*128;
            #pragma unroll
            for (int kc = 0; kc < 8; ++kc) {
                int kof = kc*16 + hi5*8;
                s16x8 bh = *(const s16x8*)(wqh + brow + kof);
                s16x8 bl = *(const s16x8*)(wql + brow + kof);
                s16x8 ah, al;
                ldv8(arow + kof, ah, al);
                tacc = MFMA32(al, bh, tacc);
                tacc = MFMA32(ah, bl, tacc);
                tacc = MFMA32(ah, bh, tacc);
            }
            #pragma unroll
            for (int r = 0; r < 16; ++r) {
                int j = jt*32 + (r & 3) + 8*(r >> 2) + 4*hi5;
                float f = tacc[r];
                BF h = bfhi(f);
                ts[s2][0][j][l31] = h;
                ts[s2][1][j][l31] = bflo(f, h);
            }
        } else if (pr == 0) {   // aux: zero ts pad rows + svec halves
            int t2 = tid - 640;                     // 0..383
            unsigned* tz = (unsigned*)smem;
            for (int z = t2; z < 2304; z += 384) {  // rows 160..191, both bufs
                int sb = z / 576, rz = z % 576;
                tz[(sb*192 + 160)*18 + rz] = 0u;
            }
            int r = t2 >> 1, hf = t2 & 1;
            if (r < 160) {
                const unsigned* vr = vb + r*128 + hf*64;
                float s = 0.f;
                #pragma unroll 8
                for (int d2 = 0; d2 < 64; ++d2)
                    s += cvec[hf*64 + d2] * bff((BF)(vr[d2] >> 16));
                svp[hf*192 + r] = s;
            }
        }
        __syncthreads();
        if (w < 15) {   // eaccum both strips of the pair
            #pragma unroll
            for (int s2 = 0; s2 < 2; ++s2) {
                int scol = (pr*2 + s2)*32 + gq*8;
                s16x8 ah[2], al[2];
                #pragma unroll
                for (int mf2 = 0; mf2 < 2; ++mf2)
                    ldv8(vb + (iw*32 + mf2*16 + li)*128 + scol, ah[mf2], al[mf2]);
                #pragma unroll
                for (int nf = 0; nf < 4; ++nf) {
                    int jr = jw*64 + nf*16 + li;
                    s16x8 bh = ld8l(&ts[s2][0][jr][gq*8]);
                    s16x8 bl = ld8l(&ts[s2][1][jr][gq*8]);
                    #pragma unroll
                    for (int mf2 = 0; mf2 < 2; ++mf2) {
                        eacc[mf2][nf] = MFMA(ah[mf2], bh, eacc[mf2][nf]);
                        eacc[mf2][nf] = MFMA(ah[mf2], bl, eacc[mf2][nf]);
                        eacc[mf2][nf] = MFMA(al[mf2], bh, eacc[mf2][nf]);
                    }
                }
            }
        }
        __syncthreads();
    }

    // ================= softmax over j =================
    if (w < 15) {
        #pragma unroll
        for (int nf = 0; nf < 4; ++nf) {
            int j = jw*64 + nf*16 + li;
            float sv = svp[j] + svp[192 + j];
            #pragma unroll
            for (int mf2 = 0; mf2 < 2; ++mf2)
                #pragma unroll
                for (int r = 0; r < 4; ++r)
                    eacc[mf2][nf][r] += sv;
        }
        #pragma unroll
        for (int mf2 = 0; mf2 < 2; ++mf2)
            #pragma unroll
            for (int r = 0; r < 4; ++r) {
                int i = iw*32 + mf2*16 + gq*4 + r;
                float m = -3.4e38f;
                #pragma unroll
                for (int nf = 0; nf < 4; ++nf) {
                    int j = jw*64 + nf*16 + li;
                    if (j < 150) m = fmaxf(m, eacc[mf2][nf][r]);
                }
                #pragma unroll
                for (int o = 1; o < 16; o <<= 1) m = fmaxf(m, __shfl_xor(m, o));
                if (li == 0) smax[jw*160 + i] = m;
            }
    }
    __syncthreads();
    if (w < 15) {
        #pragma unroll
        for (int mf2 = 0; mf2 < 2; ++mf2)
            #pragma unroll
            for (int r = 0; r < 4; ++r) {
                int i = iw*32 + mf2*16 + gq*4 + r;
                float gm = fmaxf(fmaxf(smax[i], smax[160 + i]), smax[320 + i]);
                float rs_ = 0.f;
                #pragma unroll
                for (int nf = 0; nf < 4; ++nf) {
                    int j = jw*64 + nf*16 + li;
                    float e = (j < 150) ? __expf(eacc[mf2][nf][r] - gm) : 0.f;
                    eacc[mf2][nf][r] = e;
                    rs_ += e;
                }
                #pragma unroll
                for (int o = 1; o < 16; o <<= 1) rs_ += __shfl_xor(rs_, o);
                if (li == 0) ssum[jw*160 + i] = rs_;
            }
    }
    __syncthreads();   // ts fully dead after this point
    if (w < 15) {
        #pragma unroll
        for (int mf2 = 0; mf2 < 2; ++mf2)
            #pragma unroll
            for (int r = 0; r < 4; ++r) {
                int i = iw*32 + mf2*16 + gq*4 + r;
                float inv = 1.f / (ssum[i] + ssum[160 + i] + ssum[320 + i]);
                #pragma unroll
                for (int nf = 0; nf < 4; ++nf) {
                    int j = jw*64 + nf*16 + li;
                    if (j < 160) P[i][j] = bfrne(eacc[mf2][nf][r] * inv);
                }
            }
    }
    __syncthreads();

    // ================= phase PV + fused reduce =================
    {
        const int pc = w & 7, pi = w >> 3;
        f32x4 oacc[5];
        #pragma unroll
        for (int i = 0; i < 5; ++i) oacc[i] = f32x4{0.f,0.f,0.f,0.f};
        #pragma unroll
        for (int ks = 0; ks < 5; ++ks) {
            int c = pc*16 + li;
            int j0 = ks*32 + gq*8;
            U8 t;
            #pragma unroll
            for (int e = 0; e < 8; ++e)
                t.u[e] = (BF)(vb[(j0 + e)*128 + c] >> 16);
            #pragma unroll
            for (int nf2 = 0; nf2 < 5; ++nf2) {
                int ir = pi*80 + nf2*16 + li;
                s16x8 bp = ld8l(&P[ir][ks*32 + gq*8]);
                oacc[nf2] = MFMA(t.v, bp, oacc[nf2]);
            }
        }

        float* pmax = smax;
        float* pdot = ssum;
        #pragma unroll
        for (int r = 0; r < 4; ++r) {
            int c = pc*16 + gq*4 + r;
            float mx = -3.4e38f, dt = 0.f;
            #pragma unroll
            for (int nf2 = 0; nf2 < 5; ++nf2) {
                int l = pi*80 + nf2*16 + li;
                if (l < 150) {
                    float val = gamma * oacc[nf2][r];
                    mx = fmaxf(mx, val);
                    dt = fmaf(val, Wd[c*150 + l], dt);
                }
            }
            #pragma unroll
            for (int o = 1; o < 16; o <<= 1) {
                mx = fmaxf(mx, __shfl_xor(mx, o));
                dt += __shfl_xor(dt, o);
            }
            if (li == 0) { pmax[pi*128 + c] = mx; pdot[pi*128 + c] = dt; }
        }
        __syncthreads();
        if (tid < 128) {
            out[(long)b*512 + 256 + tid] = fmaxf(pmax[tid], pmax[128 + tid]);
            dw[b*256 + tid] = pdot[tid] + pdot[128 + tid];
        } else if (tid < 256) {   // v-part combine from k1 partials
            int c2 = tid - 128;
            float m0 = vpm[(long)b*128 + c2];
            float m1 = vpm[(long)(256 + b)*128 + c2];
            out[(long)b*512 + 384 + c2] = fmaxf(m0, m1);
            dw[b*256 + 128 + c2] = vpd[(long)b*128 + c2] + vpd[(long)(256 + b)*128 + c2];
        }
    }
}

// ------------------------- tail: pw GEMM + BN + relu -------------------------
__global__ __launch_bounds__(256)
void tail_pwbn(const float* __restrict__ dw, const float* __restrict__ Wp,
               const float* __restrict__ bn_g, const float* __restrict__ bn_b,
               float* __restrict__ out)
{
    __shared__ float wp_s[256];
    __shared__ float rs[4], rs2[4];
    const int o = blockIdx.x, t = threadIdx.x;
    const int lane = t & 63, w = t >> 6;
    wp_s[t] = Wp[o * 256 + t];
    __syncthreads();
    const float4* dr = (const float4*)(dw + (long)t * 256);
    float acc = 0.f;
    #pragma unroll 8
    for (int i = 0; i < 64; ++i) {
        float4 d4 = dr[i];
        acc = fmaf(d4.x, wp_s[i*4+0], acc);
        acc = fmaf(d4.y, wp_s[i*4+1], acc);
        acc = fmaf(d4.z, wp_s[i*4+2], acc);
        acc = fmaf(d4.w, wp_s[i*4+3], acc);
    }
    float s = acc, s2 = acc * acc;
    #pragma unroll
    for (int d = 1; d < 64; d <<= 1) { s += __shfl_xor(s, d); s2 += __shfl_xor(s2, d); }
    if (lane == 0) { rs[w] = s; rs2[w] = s2; }
    __syncthreads();
    float S  = rs[0] + rs[1] + rs[2] + rs[3];
    float S2 = rs2[0] + rs2[1] + rs2[2] + rs2[3];
    float mean = S * (1.f/256.f);
    float var  = S2 * (1.f/256.f) - mean * mean;
    float sc = rsqrtf(var + 1e-5f) * bn_g[o];
    float sh = bn_b[o] - mean * sc;
    out[(long)t * 512 + o] = fmaxf(fmaf(acc, sc, sh), 0.f);
}

extern "C" void kernel_launch(void* const* d_in, const int* in_sizes, int n_in,
                              void* d_out, int out_size, void* d_ws, size_t ws_size,
                              hipStream_t stream)
{
    (void)in_sizes; (void)n_in; (void)out_size; (void)ws_size;
    const float* x    = (const float*)d_in[0];
    const float* Wv   = (const float*)d_in[1];
    const float* bv   = (const float*)d_in[2];
    const float* Wq   = (const float*)d_in[3];
    const float* bq   = (const float*)d_in[4];
    const float* Wk   = (const float*)d_in[5];
    const float* bk   = (const float*)d_in[6];  (void)bk; // row-const: cancels in softmax
    const float* gam  = (const float*)d_in[7];
    const float* Wd   = (const float*)d_in[8];
    // d_in[9] = bd, d_in[11] = bp: BN-invariant, unused.
    const float* Wp   = (const float*)d_in[10];
    const float* bn_g = (const float*)d_in[12];
    const float* bn_b = (const float*)d_in[13];
    float* out = (float*)d_out;

    char* wsb = (char*)d_ws;
    BF* wvh   = (BF*)wsb;                        // 131072 (dw overlays after k1)
    BF* wvl   = (BF*)(wsb + 131072);             // 131072
    BF* wqh   = (BF*)(wsb + 262144);             // 32768
    BF* wql   = (BF*)(wsb + 294912);             // 32768
    float* cvec = (float*)(wsb + 327680);        // 512
    unsigned* vpck = (unsigned*)(wsb + 328192);  // 20,971,520
    float* vpm  = (float*)(wsb + 21299712);      // 262144
    float* vpd  = (float*)(wsb + 21561856);      // 262144
    float* dw   = (float*)wsb;                   // overlays wvh/wvl (dead after k1)

    prep_all<<<81, 256, 0, stream>>>(Wv, Wq, Wk, bq, wvh, wvl, wqh, wql, cvec);
    k1_v<<<512, 512, 0, stream>>>(x, wvh, wvl, bv, Wd, vpck, vpm, vpd);
    k2_attn<<<256, 1024, 0, stream>>>(vpck, wqh, wql, cvec, gam, Wd, vpm, vpd,
                                      dw, out);
    tail_pwbn<<<256, 256, 0, stream>>>(dw, Wp, bn_g, bn_b, out);
}